// Round 9
// baseline (141.738 us; speedup 1.0000x reference)
//
#include <hip/hip_runtime.h>

#define NSEQ 2048
#define SCALE 0.04419417382415922f
#define LOG2E 1.44269504088896f

typedef __attribute__((ext_vector_type(8))) short short8v;
typedef __attribute__((ext_vector_type(4))) float f32x4;

__device__ __forceinline__ unsigned short f2bf(float f) {
    unsigned int u = __builtin_bit_cast(unsigned int, f);
    u += 0x7fff + ((u >> 16) & 1);
    return (unsigned short)(u >> 16);
}

__device__ __forceinline__ float exp2_fast(float x) {
    float r; asm("v_exp_f32 %0, %1" : "=v"(r) : "v"(x)); return r;
}

// pack(bf16_round(a) lo, bf16_round(b) hi) : 2 adds + 1 v_perm_b32
__device__ __forceinline__ unsigned int pack_bf16_rh(float a, float b) {
    unsigned int ua = __builtin_bit_cast(unsigned int, a) + 0x8000u;
    unsigned int ub = __builtin_bit_cast(unsigned int, b) + 0x8000u;
    return __builtin_amdgcn_perm(ub, ua, 0x07060302u);
}

// ---------------- fp32 -> bf16 convert ----------------
__global__ __launch_bounds__(256) void cvt_bf16(const float* __restrict__ in,
                                                unsigned short* __restrict__ out, int n4) {
    int i = blockIdx.x * 256 + threadIdx.x;
    if (i < n4) {
        float4 v = ((const float4*)in)[i];
        ushort4 o;
        o.x = f2bf(v.x); o.y = f2bf(v.y); o.z = f2bf(v.z); o.w = f2bf(v.w);
        ((ushort4*)out)[i] = o;
    }
}

// ---------------- bf16 GEMM, BK=64: C[M,N] = A[M,512] * W[N,512]^T + bias ----------------
template<int MODE>
__global__ __launch_bounds__(256) void gemm_bf16(
    const unsigned short* __restrict__ A,
    const unsigned short* __restrict__ W,
    const float* __restrict__ bias,
    unsigned short* __restrict__ Qws,
    unsigned short* __restrict__ Kws,
    unsigned short* __restrict__ Vtws,
    float* __restrict__ Cout)
{
    const int K = 512;
    const int BKP = 72;   // 64 + 8 pad
    __shared__ __attribute__((aligned(16))) unsigned short As[128 * BKP];
    __shared__ __attribute__((aligned(16))) unsigned short Bs[128 * BKP];

    int tid = threadIdx.x;
    int lane = tid & 63, w = tid >> 6;
    int wm = w >> 1, wn = w & 1;
    int g = lane >> 4, fr = lane & 15;
    int m0 = blockIdx.y * 128, n0 = blockIdx.x * 128;

    f32x4 acc[4][4] = {};

    for (int k0 = 0; k0 < K; k0 += 64) {
        __syncthreads();
#pragma unroll
        for (int c = 0; c < 4; ++c) {
            int chunk = tid + c * 256;            // 1024 chunks of 8 = 128x64
            int row = chunk >> 3, col = (chunk & 7) * 8;
            short8v av = *(const short8v*)(A + (size_t)(m0 + row) * K + k0 + col);
            *(short8v*)(&As[row * BKP + col]) = av;
            short8v bv = *(const short8v*)(W + (size_t)(n0 + row) * K + k0 + col);
            *(short8v*)(&Bs[row * BKP + col]) = bv;
        }
        __syncthreads();
#pragma unroll
        for (int kk = 0; kk < 2; ++kk) {
            short8v af[4], bf[4];
#pragma unroll
            for (int mi = 0; mi < 4; ++mi)
                af[mi] = *(const short8v*)(&As[(wm * 64 + mi * 16 + fr) * BKP + kk * 32 + g * 8]);
#pragma unroll
            for (int ni = 0; ni < 4; ++ni)
                bf[ni] = *(const short8v*)(&Bs[(wn * 64 + ni * 16 + fr) * BKP + kk * 32 + g * 8]);
#pragma unroll
            for (int mi = 0; mi < 4; ++mi)
#pragma unroll
                for (int ni = 0; ni < 4; ++ni)
                    acc[mi][ni] = __builtin_amdgcn_mfma_f32_16x16x32_bf16(
                        af[mi], bf[ni], acc[mi][ni], 0, 0, 0);
        }
    }

#pragma unroll
    for (int mi = 0; mi < 4; ++mi) {
#pragma unroll
        for (int ni = 0; ni < 4; ++ni) {
            int col = n0 + wn * 64 + ni * 16 + fr;
            float bb = bias[col];
#pragma unroll
            for (int r = 0; r < 4; ++r) {
                int row = m0 + wm * 64 + mi * 16 + g * 4 + r;
                float val = acc[mi][ni][r] + bb;
                if (MODE == 0) {
                    int b = row >> 11, s = row & 2047;
                    if (col < 512) {
                        int h = col >> 6, d = col & 63;
                        Qws[(((size_t)(b * 8 + h) * NSEQ + s) << 6) + d] = f2bf(val * (SCALE * LOG2E));
                    } else if (col < 1024) {
                        int c2 = col - 512; int h = c2 >> 6, d = c2 & 63;
                        Kws[(((size_t)(b * 8 + h) * NSEQ + s) << 6) + d] = f2bf(val);
                    } else {
                        int c2 = col - 1024; int h = c2 >> 6, d = c2 & 63;
                        Vtws[((size_t)(b * 8 + h) * 64 + d) * NSEQ + s] = f2bf(val);
                    }
                } else {
                    Cout[(size_t)row * 512 + col] = val;
                }
            }
        }
    }
}

// ---------------- fused attention (optionally kt-split) ----------------
// Block = 512 thr = 8 waves, one (b,h); wave w owns 16 q-rows.
// blockIdx.y = key-range part (nparts total, ktn tiles each). Fixed-max softmax
// makes partials exactly additive: O = sum(O_p)/sum(l_p).
// nparts==1: write bf16 Oat directly. nparts>1: fp32 partial O + l.
__global__ __launch_bounds__(512, 3) void attn_kernel(
    const unsigned short* __restrict__ Qws,
    const unsigned short* __restrict__ Kws,
    const unsigned short* __restrict__ Vtws,
    const float* __restrict__ A_phi,
    const float* __restrict__ gamma_p,
    unsigned short* __restrict__ Oout,
    float* __restrict__ Opart,
    float* __restrict__ Lpart,
    int nparts, int ktn)
{
    __shared__ __attribute__((aligned(16))) unsigned short Ks[2][64 * 64];
    __shared__ __attribute__((aligned(16))) unsigned short Vts[2][64 * 64];
    __shared__ __attribute__((aligned(16))) unsigned short Pl[8][16 * 64];

    int tid = threadIdx.x, lane = tid & 63, w = tid >> 6;
    int g = lane >> 4, fr = lane & 15;

    // swizzle: id%8 = XCD -> pin batch b to an XCD pair (A_phi L2 reuse)
    int id = blockIdx.x;                 // 0..511
    int b = (id & 7) >> 1, p = id & 1;
    int j = id >> 3;                     // 0..63
    int h = j & 7;
    int qt = ((j >> 3) << 1) | p;        // 0..15
    int bh = b * 8 + h;
    int q0 = qt * 128 + w * 16;          // wave's q base
    int part = blockIdx.y;
    int kt0 = part * ktn, ktE = kt0 + ktn;
    float g2 = gamma_p[0] * LOG2E;

    const unsigned short* Kb = Kws + (size_t)bh * NSEQ * 64;
    const unsigned short* Vb = Vtws + (size_t)bh * 64 * NSEQ;
    const float* Ap = A_phi + (size_t)b * NSEQ * NSEQ;

    // Q fragments
    short8v qf[2];
#pragma unroll
    for (int dc = 0; dc < 2; ++dc)
        qf[dc] = *(const short8v*)(Qws + ((size_t)bh * NSEQ + q0 + fr) * 64 + dc * 32 + g * 8);

    // staging: thread -> one 16B K chunk + one 16B V chunk
    int c = tid;
    int krow = c >> 3;                       // K: key 0..63 ; V: d 0..63
    int kchunk = c & 7;                      // 16B chunk within row
    int sw_st = (kchunk ^ (krow & 7)) * 8;   // swizzled ushort offset
    int kcol = kchunk * 8;                   // logical col (global source)

    float l_lane[4] = {};
    f32x4 o_acc[4] = {};

    // prologue: stage tile kt0
    {
        short8v k0v = *(const short8v*)(Kb + kt0 * 4096 + c * 8);
        short8v v0v = *(const short8v*)(Vb + (size_t)krow * NSEQ + kt0 * 64 + kcol);
        *(short8v*)(&Ks[0][krow * 64 + sw_st]) = k0v;
        *(short8v*)(&Vts[0][krow * 64 + sw_st]) = v0v;
    }
    __syncthreads();

    for (int kt = kt0; kt < ktE; ++kt) {
        int cur = kt & 1;

        // T14: issue next-tile global loads early
        short8v kreg, vreg;
        if (kt < ktE - 1) {
            kreg = *(const short8v*)(Kb + (kt + 1) * 4096 + c * 8);
            vreg = *(const short8v*)(Vb + (size_t)krow * NSEQ + (kt + 1) * 64 + kcol);
        }

        // A_phi tile (coalesced float4; lane's 4 consecutive keys 4*fr..4*fr+3)
        float4 av[4];
#pragma unroll
        for (int r = 0; r < 4; ++r)
            av[r] = *(const float4*)(Ap + (size_t)(q0 + g * 4 + r) * NSEQ + kt * 64 + 4 * fr);

        // S = QK^T, permuted key order: chunk kf col fr = key 4*fr+kf
        f32x4 sa[4] = {};
        __builtin_amdgcn_s_setprio(1);
#pragma unroll
        for (int kf = 0; kf < 4; ++kf) {
            int row = 4 * fr + kf;
#pragma unroll
            for (int dc = 0; dc < 2; ++dc) {
                short8v kfrag = *(const short8v*)(
                    &Ks[cur][row * 64 + (((dc * 4 + g) ^ (row & 7)) * 8)]);
                sa[kf] = __builtin_amdgcn_mfma_f32_16x16x32_bf16(qf[dc], kfrag, sa[kf], 0, 0, 0);
            }
        }
        __builtin_amdgcn_s_setprio(0);

        // P = exp2(S + g2*A); per-lane l; relay to per-wave LDS (swizzled)
#pragma unroll
        for (int r = 0; r < 4; ++r) {
            float e0 = exp2_fast(fmaf(g2, av[r].x, sa[0][r]));
            float e1 = exp2_fast(fmaf(g2, av[r].y, sa[1][r]));
            float e2 = exp2_fast(fmaf(g2, av[r].z, sa[2][r]));
            float e3 = exp2_fast(fmaf(g2, av[r].w, sa[3][r]));
            l_lane[r] += (e0 + e1) + (e2 + e3);
            int rp = g * 4 + r;
            uint2 pp;
            pp.x = pack_bf16_rh(e0, e1);
            pp.y = pack_bf16_rh(e2, e3);
            *(uint2*)(&Pl[w][rp * 64 + (((fr >> 1) ^ (rp & 7)) * 8) + (fr & 1) * 4]) = pp;
        }
        asm volatile("s_waitcnt lgkmcnt(0)" ::: "memory");

        // O += P * V
#pragma unroll
        for (int kc = 0; kc < 2; ++kc) {
            short8v pf = *(const short8v*)(
                &Pl[w][fr * 64 + (((kc * 4 + g) ^ (fr & 7)) * 8)]);
            __builtin_amdgcn_s_setprio(1);
#pragma unroll
            for (int nf = 0; nf < 4; ++nf) {
                int vrow = nf * 16 + fr;
                short8v vf = *(const short8v*)(
                    &Vts[cur][vrow * 64 + (((kc * 4 + g) ^ (vrow & 7)) * 8)]);
                o_acc[nf] = __builtin_amdgcn_mfma_f32_16x16x32_bf16(pf, vf, o_acc[nf], 0, 0, 0);
            }
            __builtin_amdgcn_s_setprio(0);
        }

        // write staged regs into the other buffer, then block-wide barrier
        if (kt < ktE - 1) {
            *(short8v*)(&Ks[cur ^ 1][krow * 64 + sw_st]) = kreg;
            *(short8v*)(&Vts[cur ^ 1][krow * 64 + sw_st]) = vreg;
        }
        __syncthreads();
    }

    // epilogue
#pragma unroll
    for (int r = 0; r < 4; ++r) {
        float l = l_lane[r];
        l += __shfl_xor(l, 1);
        l += __shfl_xor(l, 2);
        l += __shfl_xor(l, 4);
        l += __shfl_xor(l, 8);
        int qg = q0 + g * 4 + r;
        if (nparts == 1) {
            float inv = 1.0f / l;
#pragma unroll
            for (int nf = 0; nf < 4; ++nf)
                Oout[((size_t)b * NSEQ + qg) * 512 + h * 64 + nf * 16 + fr] =
                    f2bf(o_acc[nf][r] * inv);
        } else {
            float* Od = Opart + ((size_t)(part * 32 + bh) * NSEQ + qg) * 64;
#pragma unroll
            for (int nf = 0; nf < 4; ++nf)
                Od[nf * 16 + fr] = o_acc[nf][r];
            if (fr == 0)
                Lpart[(size_t)(part * 32 + bh) * NSEQ + qg] = l;
        }
    }
}

// ---------------- combine kt-split partials -> bf16 Oat ----------------
__global__ __launch_bounds__(256) void combine_parts(
    const float* __restrict__ Opart,   // [2][32][2048][64]
    const float* __restrict__ Lpart,   // [2][32][2048]
    unsigned short* __restrict__ Oat)  // [4][2048][512]
{
    int i4 = blockIdx.x * 256 + threadIdx.x;      // 0..1048575
    int i = i4 * 4;
    int bh = i >> 17;            // /(2048*64)
    int rem = i & 131071;
    int q = rem >> 6, d = rem & 63;
    const size_t half = (size_t)32 * NSEQ * 64;
    float4 o0 = *(const float4*)(Opart + i);
    float4 o1 = *(const float4*)(Opart + half + i);
    float l = Lpart[(size_t)bh * NSEQ + q] + Lpart[(size_t)32 * NSEQ + (size_t)bh * NSEQ + q];
    float inv = 1.0f / l;
    int b = bh >> 3, h = bh & 7;
    ushort4 o;
    o.x = f2bf((o0.x + o1.x) * inv);
    o.y = f2bf((o0.y + o1.y) * inv);
    o.z = f2bf((o0.z + o1.z) * inv);
    o.w = f2bf((o0.w + o1.w) * inv);
    *(ushort4*)(&Oat[((size_t)b * NSEQ + q) * 512 + h * 64 + d]) = o;
}

extern "C" void kernel_launch(void* const* d_in, const int* in_sizes, int n_in,
                              void* d_out, int out_size, void* d_ws, size_t ws_size,
                              hipStream_t stream) {
    const float* x      = (const float*)d_in[0];
    const float* A_phi  = (const float*)d_in[1];
    const float* w_qkv  = (const float*)d_in[2];
    const float* b_qkv  = (const float*)d_in[3];
    const float* w_out  = (const float*)d_in[4];
    const float* b_out  = (const float*)d_in[5];
    const float* gamma  = (const float*)d_in[6];
    float* out = (float*)d_out;

    unsigned short* xb   = (unsigned short*)d_ws;
    unsigned short* wqb  = xb  + (size_t)8192 * 512;
    unsigned short* wob  = wqb + (size_t)1536 * 512;
    unsigned short* Qws  = wob + (size_t)512 * 512;
    unsigned short* Kws  = Qws + (size_t)4 * 8 * NSEQ * 64;
    unsigned short* Vtws = Kws + (size_t)4 * 8 * NSEQ * 64;
    unsigned short* Oat  = Vtws + (size_t)4 * 8 * NSEQ * 64;
    float* Opart = (float*)(Oat + (size_t)8192 * 512);          // 2*32*2048*64 f32
    float* Lpart = Opart + (size_t)2 * 32 * NSEQ * 64;          // 2*32*2048 f32
    size_t need = (size_t)((unsigned short*)(Lpart + (size_t)2 * 32 * NSEQ) - (unsigned short*)d_ws) * 2;
    int nparts = (ws_size >= need) ? 2 : 1;
    int ktn = 32 / nparts;

    cvt_bf16<<<dim3(4096), dim3(256), 0, stream>>>(x, xb, 8192 * 512 / 4);
    cvt_bf16<<<dim3(768),  dim3(256), 0, stream>>>(w_qkv, wqb, 1536 * 512 / 4);
    cvt_bf16<<<dim3(256),  dim3(256), 0, stream>>>(w_out, wob, 512 * 512 / 4);

    gemm_bf16<0><<<dim3(12, 64), dim3(256), 0, stream>>>(
        xb, wqb, b_qkv, Qws, Kws, Vtws, nullptr);

    attn_kernel<<<dim3(512, nparts), dim3(512), 0, stream>>>(
        Qws, Kws, Vtws, A_phi, gamma, Oat, Opart, Lpart, nparts, ktn);

    if (nparts == 2)
        combine_parts<<<dim3(4096), dim3(256), 0, stream>>>(Opart, Lpart, Oat);

    gemm_bf16<1><<<dim3(4, 64), dim3(256), 0, stream>>>(
        Oat, wob, b_out, nullptr, nullptr, nullptr, out);
}

// Round 10
// 138.210 us; speedup vs baseline: 1.0255x; 1.0255x over previous
//
#include <hip/hip_runtime.h>

#define NSEQ 2048
#define SCALE 0.04419417382415922f
#define LOG2E 1.44269504088896f

typedef __attribute__((ext_vector_type(8))) short short8v;
typedef __attribute__((ext_vector_type(4))) float f32x4;

__device__ __forceinline__ unsigned short f2bf(float f) {
    unsigned int u = __builtin_bit_cast(unsigned int, f);
    u += 0x7fff + ((u >> 16) & 1);
    return (unsigned short)(u >> 16);
}

__device__ __forceinline__ float exp2_fast(float x) {
    float r; asm("v_exp_f32 %0, %1" : "=v"(r) : "v"(x)); return r;
}

// pack(bf16_round(a) lo, bf16_round(b) hi) : 2 adds + 1 v_perm_b32
__device__ __forceinline__ unsigned int pack_bf16_rh(float a, float b) {
    unsigned int ua = __builtin_bit_cast(unsigned int, a) + 0x8000u;
    unsigned int ub = __builtin_bit_cast(unsigned int, b) + 0x8000u;
    return __builtin_amdgcn_perm(ub, ua, 0x07060302u);
}

// ---------------- fp32 -> bf16 convert ----------------
__global__ __launch_bounds__(256) void cvt_bf16(const float* __restrict__ in,
                                                unsigned short* __restrict__ out, int n4) {
    int i = blockIdx.x * 256 + threadIdx.x;
    if (i < n4) {
        float4 v = ((const float4*)in)[i];
        ushort4 o;
        o.x = f2bf(v.x); o.y = f2bf(v.y); o.z = f2bf(v.z); o.w = f2bf(v.w);
        ((ushort4*)out)[i] = o;
    }
}

// ---------------- bf16 GEMM, BK=64: C[M,N] = A[M,512] * W[N,512]^T + bias ----------------
template<int MODE>
__global__ __launch_bounds__(256) void gemm_bf16(
    const unsigned short* __restrict__ A,
    const unsigned short* __restrict__ W,
    const float* __restrict__ bias,
    unsigned short* __restrict__ Qws,
    unsigned short* __restrict__ Kws,
    unsigned short* __restrict__ Vtws,
    float* __restrict__ Cout)
{
    const int K = 512;
    const int BKP = 72;   // 64 + 8 pad
    __shared__ __attribute__((aligned(16))) unsigned short As[128 * BKP];
    __shared__ __attribute__((aligned(16))) unsigned short Bs[128 * BKP];

    int tid = threadIdx.x;
    int lane = tid & 63, w = tid >> 6;
    int wm = w >> 1, wn = w & 1;
    int g = lane >> 4, fr = lane & 15;
    int m0 = blockIdx.y * 128, n0 = blockIdx.x * 128;

    f32x4 acc[4][4] = {};

    for (int k0 = 0; k0 < K; k0 += 64) {
        __syncthreads();
#pragma unroll
        for (int c = 0; c < 4; ++c) {
            int chunk = tid + c * 256;            // 1024 chunks of 8 = 128x64
            int row = chunk >> 3, col = (chunk & 7) * 8;
            short8v av = *(const short8v*)(A + (size_t)(m0 + row) * K + k0 + col);
            *(short8v*)(&As[row * BKP + col]) = av;
            short8v bv = *(const short8v*)(W + (size_t)(n0 + row) * K + k0 + col);
            *(short8v*)(&Bs[row * BKP + col]) = bv;
        }
        __syncthreads();
#pragma unroll
        for (int kk = 0; kk < 2; ++kk) {
            short8v af[4], bf[4];
#pragma unroll
            for (int mi = 0; mi < 4; ++mi)
                af[mi] = *(const short8v*)(&As[(wm * 64 + mi * 16 + fr) * BKP + kk * 32 + g * 8]);
#pragma unroll
            for (int ni = 0; ni < 4; ++ni)
                bf[ni] = *(const short8v*)(&Bs[(wn * 64 + ni * 16 + fr) * BKP + kk * 32 + g * 8]);
#pragma unroll
            for (int mi = 0; mi < 4; ++mi)
#pragma unroll
                for (int ni = 0; ni < 4; ++ni)
                    acc[mi][ni] = __builtin_amdgcn_mfma_f32_16x16x32_bf16(
                        af[mi], bf[ni], acc[mi][ni], 0, 0, 0);
        }
    }

#pragma unroll
    for (int mi = 0; mi < 4; ++mi) {
#pragma unroll
        for (int ni = 0; ni < 4; ++ni) {
            int col = n0 + wn * 64 + ni * 16 + fr;
            float bb = bias[col];
#pragma unroll
            for (int r = 0; r < 4; ++r) {
                int row = m0 + wm * 64 + mi * 16 + g * 4 + r;
                float val = acc[mi][ni][r] + bb;
                if (MODE == 0) {
                    int b = row >> 11, s = row & 2047;
                    if (col < 512) {
                        int h = col >> 6, d = col & 63;
                        Qws[(((size_t)(b * 8 + h) * NSEQ + s) << 6) + d] = f2bf(val * (SCALE * LOG2E));
                    } else if (col < 1024) {
                        int c2 = col - 512; int h = c2 >> 6, d = c2 & 63;
                        Kws[(((size_t)(b * 8 + h) * NSEQ + s) << 6) + d] = f2bf(val);
                    } else {
                        int c2 = col - 1024; int h = c2 >> 6, d = c2 & 63;
                        Vtws[((size_t)(b * 8 + h) * 64 + d) * NSEQ + s] = f2bf(val);
                    }
                } else {
                    Cout[(size_t)row * 512 + col] = val;
                }
            }
        }
    }
}

// ---------------- fused attention, swapped-QK / in-register P ----------------
// Block = 512 thr = 8 waves, one (b,h); wave w owns 16 q-rows (q = q0+fr).
// S^T = mfma(A=K_perm, B=Q): lane(g,fr) holds S^T[key sigma(kf,g*4+r)][q=fr]
// with sigma(kf,slot)=32*(kf>>1)+8g+4*(kf&1)+r. P stays in-lane; PV B-frag
// pa[kc] built by cvt_pk pairs; O^T = mfma(A=V^T-frag, B=pa). No P LDS relay.
// K stored in LDS at permuted row rho(key); K/V tiles XOR-swizzled, dbuf, 32KB.
__global__ __launch_bounds__(512, 2) void attn_kernel(
    const unsigned short* __restrict__ Qws,
    const unsigned short* __restrict__ Kws,
    const unsigned short* __restrict__ Vtws,
    const float* __restrict__ A_phi,
    const float* __restrict__ gamma_p,
    unsigned short* __restrict__ Oout)
{
    __shared__ __attribute__((aligned(16))) unsigned short Ks[2][64 * 64];
    __shared__ __attribute__((aligned(16))) unsigned short Vts[2][64 * 64];

    int tid = threadIdx.x, lane = tid & 63, w = tid >> 6;
    int g = lane >> 4, fr = lane & 15;

    // swizzle: id%8 = XCD -> pin batch b to an XCD pair (A_phi L2 reuse)
    int id = blockIdx.x;                 // 0..511
    int b = (id & 7) >> 1, p = id & 1;
    int j = id >> 3;                     // 0..63
    int h = j & 7;
    int qt = ((j >> 3) << 1) | p;        // 0..15
    int bh = b * 8 + h;
    int q0 = qt * 128 + w * 16;          // wave's q base
    float g2 = gamma_p[0] * LOG2E;

    const unsigned short* Kb = Kws + (size_t)bh * NSEQ * 64;
    const unsigned short* Vb = Vtws + (size_t)bh * 64 * NSEQ;
    const float* Ap = A_phi + (size_t)b * NSEQ * NSEQ + (size_t)q0 * NSEQ;

    // Q fragments (B-operand: col=q=fr, k=d) — same loads as before
    short8v qf[2];
#pragma unroll
    for (int dc = 0; dc < 2; ++dc)
        qf[dc] = *(const short8v*)(Qws + ((size_t)bh * NSEQ + q0 + fr) * 64 + dc * 32 + g * 8);

    // staging: thread -> one 16B K chunk + one 16B V chunk
    int c = tid;
    int krow = c >> 3;                       // K: key 0..63 ; V: d 0..63
    int kchunk = c & 7;
    // K row permute rho(key): key -> LDS row 16*kf + slot
    int rhoK = 16 * (2 * (krow >> 5) + ((krow >> 2) & 1)) + 4 * ((krow >> 3) & 3) + (krow & 3);
    int swK = (kchunk ^ (rhoK & 7)) * 8;     // XOR swizzle vs LDS-row low bits
    int swV = (kchunk ^ (krow & 7)) * 8;
    int kcol = kchunk * 8;

    float l_lane = 0.f;
    f32x4 o_acc[4] = {};

    // prologue: stage tile 0
    {
        short8v k0v = *(const short8v*)(Kb + c * 8);
        short8v v0v = *(const short8v*)(Vb + (size_t)krow * NSEQ + kcol);
        *(short8v*)(&Ks[0][rhoK * 64 + swK]) = k0v;
        *(short8v*)(&Vts[0][krow * 64 + swV]) = v0v;
    }
    __syncthreads();

    for (int kt = 0; kt < NSEQ / 64; ++kt) {
        int cur = kt & 1;

        // T14: issue next-tile global loads early
        short8v kreg, vreg;
        if (kt < NSEQ / 64 - 1) {
            kreg = *(const short8v*)(Kb + (kt + 1) * 4096 + c * 8);
            vreg = *(const short8v*)(Vb + (size_t)krow * NSEQ + (kt + 1) * 64 + kcol);
        }

        // A_phi: av[kf] = 4 consecutive keys sigma(kf, g*4 + 0..3) at row q0+fr
        float4 av[4];
#pragma unroll
        for (int kf = 0; kf < 4; ++kf)
            av[kf] = *(const float4*)(Ap + (size_t)fr * NSEQ + kt * 64
                                      + 32 * (kf >> 1) + 8 * g + 4 * (kf & 1));

        // S^T = mfma(A=K_perm chunk, B=Q)
        f32x4 sa[4] = {};
        __builtin_amdgcn_s_setprio(1);
#pragma unroll
        for (int kf = 0; kf < 4; ++kf) {
#pragma unroll
            for (int dc = 0; dc < 2; ++dc) {
                short8v kfrag = *(const short8v*)(
                    &Ks[cur][(16 * kf + fr) * 64 + (((dc * 4 + g) ^ (fr & 7)) * 8)]);
                sa[kf] = __builtin_amdgcn_mfma_f32_16x16x32_bf16(kfrag, qf[dc], sa[kf], 0, 0, 0);
            }
        }
        __builtin_amdgcn_s_setprio(0);

        // P = exp2(S + g2*A) in place, accumulate l (all 16 values this lane)
#pragma unroll
        for (int kf = 0; kf < 4; ++kf) {
            float e0 = exp2_fast(fmaf(g2, av[kf].x, sa[kf][0]));
            float e1 = exp2_fast(fmaf(g2, av[kf].y, sa[kf][1]));
            float e2 = exp2_fast(fmaf(g2, av[kf].z, sa[kf][2]));
            float e3 = exp2_fast(fmaf(g2, av[kf].w, sa[kf][3]));
            sa[kf][0] = e0; sa[kf][1] = e1; sa[kf][2] = e2; sa[kf][3] = e3;
            l_lane += (e0 + e1) + (e2 + e3);
        }

        // pa[kc]: PV B-frag, keys kc*32 + 8g + e (e=0..7), built in-lane
        short8v pa[2];
#pragma unroll
        for (int kc = 0; kc < 2; ++kc) {
            unsigned int u0 = pack_bf16_rh(sa[2 * kc][0],     sa[2 * kc][1]);
            unsigned int u1 = pack_bf16_rh(sa[2 * kc][2],     sa[2 * kc][3]);
            unsigned int u2 = pack_bf16_rh(sa[2 * kc + 1][0], sa[2 * kc + 1][1]);
            unsigned int u3 = pack_bf16_rh(sa[2 * kc + 1][2], sa[2 * kc + 1][3]);
            union { unsigned int u[4]; short8v v; } pu;
            pu.u[0] = u0; pu.u[1] = u1; pu.u[2] = u2; pu.u[3] = u3;
            pa[kc] = pu.v;
        }

        // O^T += mfma(A=V^T-frag, B=pa)
#pragma unroll
        for (int kc = 0; kc < 2; ++kc) {
            __builtin_amdgcn_s_setprio(1);
#pragma unroll
            for (int nf = 0; nf < 4; ++nf) {
                int vrow = nf * 16 + fr;
                short8v vf = *(const short8v*)(
                    &Vts[cur][vrow * 64 + (((kc * 4 + g) ^ (fr & 7)) * 8)]);
                o_acc[nf] = __builtin_amdgcn_mfma_f32_16x16x32_bf16(vf, pa[kc], o_acc[nf], 0, 0, 0);
            }
            __builtin_amdgcn_s_setprio(0);
        }

        // write staged regs into the other buffer, then block-wide barrier
        if (kt < NSEQ / 64 - 1) {
            *(short8v*)(&Ks[cur ^ 1][rhoK * 64 + swK]) = kreg;
            *(short8v*)(&Vts[cur ^ 1][krow * 64 + swV]) = vreg;
        }
        __syncthreads();
    }

    // epilogue: l reduce across the 4 g-lanes (q=fr is lane-local)
    float l = l_lane;
    l += __shfl_xor(l, 16);
    l += __shfl_xor(l, 32);
    float inv = 1.0f / l;
    int qg = q0 + fr;
    // o_acc[nf][r] = O[q0+fr][nf*16 + g*4 + r]
#pragma unroll
    for (int nf = 0; nf < 4; ++nf) {
        unsigned int w01 = pack_bf16_rh(o_acc[nf][0] * inv, o_acc[nf][1] * inv);
        unsigned int w23 = pack_bf16_rh(o_acc[nf][2] * inv, o_acc[nf][3] * inv);
        size_t base = ((size_t)b * NSEQ + qg) * 512 + h * 64 + nf * 16 + g * 4;
        *(unsigned int*)(&Oout[base])     = w01;
        *(unsigned int*)(&Oout[base + 2]) = w23;
    }
}

extern "C" void kernel_launch(void* const* d_in, const int* in_sizes, int n_in,
                              void* d_out, int out_size, void* d_ws, size_t ws_size,
                              hipStream_t stream) {
    const float* x      = (const float*)d_in[0];
    const float* A_phi  = (const float*)d_in[1];
    const float* w_qkv  = (const float*)d_in[2];
    const float* b_qkv  = (const float*)d_in[3];
    const float* w_out  = (const float*)d_in[4];
    const float* b_out  = (const float*)d_in[5];
    const float* gamma  = (const float*)d_in[6];
    float* out = (float*)d_out;

    unsigned short* xb   = (unsigned short*)d_ws;
    unsigned short* wqb  = xb  + (size_t)8192 * 512;
    unsigned short* wob  = wqb + (size_t)1536 * 512;
    unsigned short* Qws  = wob + (size_t)512 * 512;
    unsigned short* Kws  = Qws + (size_t)4 * 8 * NSEQ * 64;
    unsigned short* Vtws = Kws + (size_t)4 * 8 * NSEQ * 64;
    unsigned short* Oat  = Vtws + (size_t)4 * 8 * NSEQ * 64;

    cvt_bf16<<<dim3(4096), dim3(256), 0, stream>>>(x, xb, 8192 * 512 / 4);
    cvt_bf16<<<dim3(768),  dim3(256), 0, stream>>>(w_qkv, wqb, 1536 * 512 / 4);
    cvt_bf16<<<dim3(256),  dim3(256), 0, stream>>>(w_out, wob, 512 * 512 / 4);

    gemm_bf16<0><<<dim3(12, 64), dim3(256), 0, stream>>>(
        xb, wqb, b_qkv, Qws, Kws, Vtws, nullptr);

    attn_kernel<<<dim3(512), dim3(512), 0, stream>>>(
        Qws, Kws, Vtws, A_phi, gamma, Oat);

    gemm_bf16<1><<<dim3(4, 64), dim3(256), 0, stream>>>(
        Oat, wob, b_out, nullptr, nullptr, nullptr, out);
}

// Round 11
// 133.698 us; speedup vs baseline: 1.0601x; 1.0337x over previous
//
#include <hip/hip_runtime.h>

#define NSEQ 2048
#define SCALE 0.04419417382415922f
#define LOG2E 1.44269504088896f

typedef __attribute__((ext_vector_type(8))) short short8v;
typedef __attribute__((ext_vector_type(4))) float f32x4;

#define GLOAD_LDS16(g, l) __builtin_amdgcn_global_load_lds( \
    (const __attribute__((address_space(1))) void*)(g),     \
    (__attribute__((address_space(3))) void*)(l), 16, 0, 0)

__device__ __forceinline__ unsigned short f2bf(float f) {
    unsigned int u = __builtin_bit_cast(unsigned int, f);
    u += 0x7fff + ((u >> 16) & 1);
    return (unsigned short)(u >> 16);
}

__device__ __forceinline__ float exp2_fast(float x) {
    float r; asm("v_exp_f32 %0, %1" : "=v"(r) : "v"(x)); return r;
}

// pack(bf16_round(a) lo, bf16_round(b) hi) : 2 adds + 1 v_perm_b32
__device__ __forceinline__ unsigned int pack_bf16_rh(float a, float b) {
    unsigned int ua = __builtin_bit_cast(unsigned int, a) + 0x8000u;
    unsigned int ub = __builtin_bit_cast(unsigned int, b) + 0x8000u;
    return __builtin_amdgcn_perm(ub, ua, 0x07060302u);
}

// ---------------- fp32 -> bf16 convert ----------------
__global__ __launch_bounds__(256) void cvt_bf16(const float* __restrict__ in,
                                                unsigned short* __restrict__ out, int n4) {
    int i = blockIdx.x * 256 + threadIdx.x;
    if (i < n4) {
        float4 v = ((const float4*)in)[i];
        ushort4 o;
        o.x = f2bf(v.x); o.y = f2bf(v.y); o.z = f2bf(v.z); o.w = f2bf(v.w);
        ((ushort4*)out)[i] = o;
    }
}

// ---------------- bf16 GEMM, BK=64, global_load_lds staging ----------------
// Linear LDS [128][64], XOR-swizzled: LDS[row][c8] = G[row][c8 ^ (row&7)];
// frag reads apply the same XOR (both-sides pattern).
template<int MODE>
__global__ __launch_bounds__(256) void gemm_bf16(
    const unsigned short* __restrict__ A,
    const unsigned short* __restrict__ W,
    const float* __restrict__ bias,
    unsigned short* __restrict__ Qws,
    unsigned short* __restrict__ Kws,
    unsigned short* __restrict__ Vtws,
    float* __restrict__ Cout)
{
    __shared__ __attribute__((aligned(16))) unsigned short As[128 * 64];
    __shared__ __attribute__((aligned(16))) unsigned short Bs[128 * 64];

    int tid = threadIdx.x;
    int lane = tid & 63, w = tid >> 6;
    int wm = w >> 1, wn = w & 1;
    int g = lane >> 4, fr = lane & 15;
    int m0 = blockIdx.y * 128, n0 = blockIdx.x * 128;

    f32x4 acc[4][4] = {};

    for (int k0 = 0; k0 < 512; k0 += 64) {
        __syncthreads();
#pragma unroll
        for (int c = 0; c < 4; ++c) {
            int chunk = tid + c * 256;            // 1024 chunks of 16B = 128x64
            int row = chunk >> 3, c8 = chunk & 7;
            int gcol = (c8 ^ (row & 7)) * 8;      // pre-swizzled global col
            GLOAD_LDS16(A + (size_t)(m0 + row) * 512 + k0 + gcol, &As[chunk * 8]);
            GLOAD_LDS16(W + (size_t)(n0 + row) * 512 + k0 + gcol, &Bs[chunk * 8]);
        }
        __syncthreads();
#pragma unroll
        for (int kk = 0; kk < 2; ++kk) {
            short8v af[4], bf[4];
#pragma unroll
            for (int mi = 0; mi < 4; ++mi) {
                int row = wm * 64 + mi * 16 + fr;
                af[mi] = *(const short8v*)(&As[row * 64 + (((kk * 4 + g) ^ (row & 7)) * 8)]);
            }
#pragma unroll
            for (int ni = 0; ni < 4; ++ni) {
                int row = wn * 64 + ni * 16 + fr;
                bf[ni] = *(const short8v*)(&Bs[row * 64 + (((kk * 4 + g) ^ (row & 7)) * 8)]);
            }
#pragma unroll
            for (int mi = 0; mi < 4; ++mi)
#pragma unroll
                for (int ni = 0; ni < 4; ++ni)
                    acc[mi][ni] = __builtin_amdgcn_mfma_f32_16x16x32_bf16(
                        af[mi], bf[ni], acc[mi][ni], 0, 0, 0);
        }
    }

#pragma unroll
    for (int mi = 0; mi < 4; ++mi) {
#pragma unroll
        for (int ni = 0; ni < 4; ++ni) {
            int col = n0 + wn * 64 + ni * 16 + fr;
            float bb = bias[col];
#pragma unroll
            for (int r = 0; r < 4; ++r) {
                int row = m0 + wm * 64 + mi * 16 + g * 4 + r;
                float val = acc[mi][ni][r] + bb;
                if (MODE == 0) {
                    int b = row >> 11, s = row & 2047;
                    if (col < 512) {
                        int h = col >> 6, d = col & 63;
                        Qws[(((size_t)(b * 8 + h) * NSEQ + s) << 6) + d] = f2bf(val * (SCALE * LOG2E));
                    } else if (col < 1024) {
                        int c2 = col - 512; int h = c2 >> 6, d = c2 & 63;
                        Kws[(((size_t)(b * 8 + h) * NSEQ + s) << 6) + d] = f2bf(val);
                    } else {
                        int c2 = col - 1024; int h = c2 >> 6, d = c2 & 63;
                        Vtws[((size_t)(b * 8 + h) * 64 + d) * NSEQ + s] = f2bf(val);
                    }
                } else {
                    Cout[(size_t)row * 512 + col] = val;
                }
            }
        }
    }
}

// ---------------- fused attention (R8 structure + av prefetch + gload_lds) ----
// Block = 512 thr = 8 waves, one (b,h); wave w owns 16 q-rows.
// K/V tiles double-buffered via global_load_lds (linear dest, pre-swizzled
// source, swizzled read). A_phi tile register-prefetched one iter ahead.
// Fixed-max softmax: P = exp2(S + g2*A_phi). Q pre-scaled by SCALE*LOG2E.
__global__ __launch_bounds__(512, 2) void attn_kernel(
    const unsigned short* __restrict__ Qws,
    const unsigned short* __restrict__ Kws,
    const unsigned short* __restrict__ Vtws,
    const float* __restrict__ A_phi,
    const float* __restrict__ gamma_p,
    unsigned short* __restrict__ Oout)
{
    __shared__ __attribute__((aligned(16))) unsigned short Ks[2][64 * 64];
    __shared__ __attribute__((aligned(16))) unsigned short Vts[2][64 * 64];
    __shared__ __attribute__((aligned(16))) unsigned short Pl[8][16 * 64];

    int tid = threadIdx.x, lane = tid & 63, w = tid >> 6;
    int g = lane >> 4, fr = lane & 15;

    // swizzle: id%8 = XCD -> pin batch b to an XCD pair (A_phi L2 reuse)
    int id = blockIdx.x;                 // 0..511
    int b = (id & 7) >> 1, p = id & 1;
    int j = id >> 3;                     // 0..63
    int h = j & 7;
    int qt = ((j >> 3) << 1) | p;        // 0..15
    int bh = b * 8 + h;
    int q0 = qt * 128 + w * 16;          // wave's q base
    float g2 = gamma_p[0] * LOG2E;

    const unsigned short* Kb = Kws + (size_t)bh * NSEQ * 64;
    const unsigned short* Vb = Vtws + (size_t)bh * 64 * NSEQ;
    const float* Ap = A_phi + (size_t)b * NSEQ * NSEQ;

    // Q fragments
    short8v qf[2];
#pragma unroll
    for (int dc = 0; dc < 2; ++dc)
        qf[dc] = *(const short8v*)(Qws + ((size_t)bh * NSEQ + q0 + fr) * 64 + dc * 32 + g * 8);

    // staging: thread -> one 16B K chunk + one 16B V chunk (pre-swizzled source)
    int c = tid;
    int krow = c >> 3;                       // K: key 0..63 ; V: d 0..63
    int kchunk = c & 7;
    int gcol = (kchunk ^ (krow & 7)) * 8;    // swizzled global col (bf16 units)
    const unsigned short* Ksrc = Kb + krow * 64 + gcol;
    const unsigned short* Vsrc = Vb + (size_t)krow * NSEQ + gcol;

    float l_lane[4] = {};
    f32x4 o_acc[4] = {};

    // prologue: stage tile 0 (async -> LDS), prefetch A_phi tile 0 to regs
    GLOAD_LDS16(Ksrc, &Ks[0][c * 8]);
    GLOAD_LDS16(Vsrc, &Vts[0][c * 8]);
    float4 av_n[4];
#pragma unroll
    for (int r = 0; r < 4; ++r)
        av_n[r] = *(const float4*)(Ap + (size_t)(q0 + g * 4 + r) * NSEQ + 4 * fr);
    __syncthreads();

    for (int kt = 0; kt < NSEQ / 64; ++kt) {
        int cur = kt & 1;

        // async-stage next K/V tile into the other buffer (no regs)
        if (kt < NSEQ / 64 - 1) {
            GLOAD_LDS16(Ksrc + (kt + 1) * 4096, &Ks[cur ^ 1][c * 8]);
            GLOAD_LDS16(Vsrc + (kt + 1) * 64, &Vts[cur ^ 1][c * 8]);
        }

        // consume prefetched A_phi; issue next-tile A_phi loads now
        float4 av[4];
#pragma unroll
        for (int r = 0; r < 4; ++r) av[r] = av_n[r];
        if (kt < NSEQ / 64 - 1) {
#pragma unroll
            for (int r = 0; r < 4; ++r)
                av_n[r] = *(const float4*)(Ap + (size_t)(q0 + g * 4 + r) * NSEQ
                                           + (kt + 1) * 64 + 4 * fr);
        }

        // S = QK^T, permuted key order: chunk kf col fr = key 4*fr+kf
        f32x4 sa[4] = {};
        __builtin_amdgcn_s_setprio(1);
#pragma unroll
        for (int kf = 0; kf < 4; ++kf) {
            int row = 4 * fr + kf;
#pragma unroll
            for (int dc = 0; dc < 2; ++dc) {
                short8v kfrag = *(const short8v*)(
                    &Ks[cur][row * 64 + (((dc * 4 + g) ^ (row & 7)) * 8)]);
                sa[kf] = __builtin_amdgcn_mfma_f32_16x16x32_bf16(qf[dc], kfrag, sa[kf], 0, 0, 0);
            }
        }
        __builtin_amdgcn_s_setprio(0);

        // P = exp2(S + g2*A); per-lane l; relay to per-wave LDS (swizzled)
#pragma unroll
        for (int r = 0; r < 4; ++r) {
            float e0 = exp2_fast(fmaf(g2, av[r].x, sa[0][r]));
            float e1 = exp2_fast(fmaf(g2, av[r].y, sa[1][r]));
            float e2 = exp2_fast(fmaf(g2, av[r].z, sa[2][r]));
            float e3 = exp2_fast(fmaf(g2, av[r].w, sa[3][r]));
            l_lane[r] += (e0 + e1) + (e2 + e3);
            int rp = g * 4 + r;
            uint2 pp;
            pp.x = pack_bf16_rh(e0, e1);
            pp.y = pack_bf16_rh(e2, e3);
            *(uint2*)(&Pl[w][rp * 64 + (((fr >> 1) ^ (rp & 7)) * 8) + (fr & 1) * 4]) = pp;
        }
        asm volatile("s_waitcnt lgkmcnt(0)" ::: "memory");

        // O += P * V
#pragma unroll
        for (int kc = 0; kc < 2; ++kc) {
            short8v pf = *(const short8v*)(
                &Pl[w][fr * 64 + (((kc * 4 + g) ^ (fr & 7)) * 8)]);
            __builtin_amdgcn_s_setprio(1);
#pragma unroll
            for (int nf = 0; nf < 4; ++nf) {
                int vrow = nf * 16 + fr;
                short8v vf = *(const short8v*)(
                    &Vts[cur][vrow * 64 + (((kc * 4 + g) ^ (vrow & 7)) * 8)]);
                o_acc[nf] = __builtin_amdgcn_mfma_f32_16x16x32_bf16(pf, vf, o_acc[nf], 0, 0, 0);
            }
            __builtin_amdgcn_s_setprio(0);
        }

        __syncthreads();
    }

    // epilogue: reduce l across 16-lane group, normalize, store bf16
#pragma unroll
    for (int r = 0; r < 4; ++r) {
        float l = l_lane[r];
        l += __shfl_xor(l, 1);
        l += __shfl_xor(l, 2);
        l += __shfl_xor(l, 4);
        l += __shfl_xor(l, 8);
        float inv = 1.0f / l;
        int qg = q0 + g * 4 + r;
#pragma unroll
        for (int nf = 0; nf < 4; ++nf)
            Oout[((size_t)b * NSEQ + qg) * 512 + h * 64 + nf * 16 + fr] =
                f2bf(o_acc[nf][r] * inv);
    }
}

extern "C" void kernel_launch(void* const* d_in, const int* in_sizes, int n_in,
                              void* d_out, int out_size, void* d_ws, size_t ws_size,
                              hipStream_t stream) {
    const float* x      = (const float*)d_in[0];
    const float* A_phi  = (const float*)d_in[1];
    const float* w_qkv  = (const float*)d_in[2];
    const float* b_qkv  = (const float*)d_in[3];
    const float* w_out  = (const float*)d_in[4];
    const float* b_out  = (const float*)d_in[5];
    const float* gamma  = (const float*)d_in[6];
    float* out = (float*)d_out;

    unsigned short* xb   = (unsigned short*)d_ws;
    unsigned short* wqb  = xb  + (size_t)8192 * 512;
    unsigned short* wob  = wqb + (size_t)1536 * 512;
    unsigned short* Qws  = wob + (size_t)512 * 512;
    unsigned short* Kws  = Qws + (size_t)4 * 8 * NSEQ * 64;
    unsigned short* Vtws = Kws + (size_t)4 * 8 * NSEQ * 64;
    unsigned short* Oat  = Vtws + (size_t)4 * 8 * NSEQ * 64;

    cvt_bf16<<<dim3(4096), dim3(256), 0, stream>>>(x, xb, 8192 * 512 / 4);
    cvt_bf16<<<dim3(768),  dim3(256), 0, stream>>>(w_qkv, wqb, 1536 * 512 / 4);
    cvt_bf16<<<dim3(256),  dim3(256), 0, stream>>>(w_out, wob, 512 * 512 / 4);

    gemm_bf16<0><<<dim3(12, 64), dim3(256), 0, stream>>>(
        xb, wqb, b_qkv, Qws, Kws, Vtws, nullptr);

    attn_kernel<<<dim3(512), dim3(512), 0, stream>>>(
        Qws, Kws, Vtws, A_phi, gamma, Oat);

    gemm_bf16<1><<<dim3(4, 64), dim3(256), 0, stream>>>(
        Oat, wob, b_out, nullptr, nullptr, nullptr, out);
}

// Round 12
// 124.256 us; speedup vs baseline: 1.1407x; 1.0760x over previous
//
#include <hip/hip_runtime.h>

#define NSEQ 2048
#define SCALE 0.04419417382415922f
#define LOG2E 1.44269504088896f

typedef __attribute__((ext_vector_type(8))) short short8v;
typedef __attribute__((ext_vector_type(4))) float f32x4;

#define GLOAD_LDS16(g, l) __builtin_amdgcn_global_load_lds( \
    (const __attribute__((address_space(1))) void*)(g),     \
    (__attribute__((address_space(3))) void*)(l), 16, 0, 0)

__device__ __forceinline__ unsigned short f2bf(float f) {
    unsigned int u = __builtin_bit_cast(unsigned int, f);
    u += 0x7fff + ((u >> 16) & 1);
    return (unsigned short)(u >> 16);
}

__device__ __forceinline__ float exp2_fast(float x) {
    float r; asm("v_exp_f32 %0, %1" : "=v"(r) : "v"(x)); return r;
}

// pack(bf16_round(a) lo, bf16_round(b) hi) : 2 adds + 1 v_perm_b32
__device__ __forceinline__ unsigned int pack_bf16_rh(float a, float b) {
    unsigned int ua = __builtin_bit_cast(unsigned int, a) + 0x8000u;
    unsigned int ub = __builtin_bit_cast(unsigned int, b) + 0x8000u;
    return __builtin_amdgcn_perm(ub, ua, 0x07060302u);
}

// ---------------- fp32 -> bf16 convert ----------------
__global__ __launch_bounds__(256) void cvt_bf16(const float* __restrict__ in,
                                                unsigned short* __restrict__ out, int n4) {
    int i = blockIdx.x * 256 + threadIdx.x;
    if (i < n4) {
        float4 v = ((const float4*)in)[i];
        ushort4 o;
        o.x = f2bf(v.x); o.y = f2bf(v.y); o.z = f2bf(v.z); o.w = f2bf(v.w);
        ((ushort4*)out)[i] = o;
    }
}

// ---------------- bf16 GEMM, BK=64, global_load_lds staging (R11, kept) ------
template<int MODE>
__global__ __launch_bounds__(256) void gemm_bf16(
    const unsigned short* __restrict__ A,
    const unsigned short* __restrict__ W,
    const float* __restrict__ bias,
    unsigned short* __restrict__ Qws,
    unsigned short* __restrict__ Kws,
    unsigned short* __restrict__ Vtws,
    float* __restrict__ Cout)
{
    __shared__ __attribute__((aligned(16))) unsigned short As[128 * 64];
    __shared__ __attribute__((aligned(16))) unsigned short Bs[128 * 64];

    int tid = threadIdx.x;
    int lane = tid & 63, w = tid >> 6;
    int wm = w >> 1, wn = w & 1;
    int g = lane >> 4, fr = lane & 15;
    int m0 = blockIdx.y * 128, n0 = blockIdx.x * 128;

    f32x4 acc[4][4] = {};

    for (int k0 = 0; k0 < 512; k0 += 64) {
        __syncthreads();
#pragma unroll
        for (int c = 0; c < 4; ++c) {
            int chunk = tid + c * 256;            // 1024 chunks of 16B = 128x64
            int row = chunk >> 3, c8 = chunk & 7;
            int gcol = (c8 ^ (row & 7)) * 8;      // pre-swizzled global col
            GLOAD_LDS16(A + (size_t)(m0 + row) * 512 + k0 + gcol, &As[chunk * 8]);
            GLOAD_LDS16(W + (size_t)(n0 + row) * 512 + k0 + gcol, &Bs[chunk * 8]);
        }
        __syncthreads();
#pragma unroll
        for (int kk = 0; kk < 2; ++kk) {
            short8v af[4], bf[4];
#pragma unroll
            for (int mi = 0; mi < 4; ++mi) {
                int row = wm * 64 + mi * 16 + fr;
                af[mi] = *(const short8v*)(&As[row * 64 + (((kk * 4 + g) ^ (row & 7)) * 8)]);
            }
#pragma unroll
            for (int ni = 0; ni < 4; ++ni) {
                int row = wn * 64 + ni * 16 + fr;
                bf[ni] = *(const short8v*)(&Bs[row * 64 + (((kk * 4 + g) ^ (row & 7)) * 8)]);
            }
#pragma unroll
            for (int mi = 0; mi < 4; ++mi)
#pragma unroll
                for (int ni = 0; ni < 4; ++ni)
                    acc[mi][ni] = __builtin_amdgcn_mfma_f32_16x16x32_bf16(
                        af[mi], bf[ni], acc[mi][ni], 0, 0, 0);
        }
    }

#pragma unroll
    for (int mi = 0; mi < 4; ++mi) {
#pragma unroll
        for (int ni = 0; ni < 4; ++ni) {
            int col = n0 + wn * 64 + ni * 16 + fr;
            float bb = bias[col];
#pragma unroll
            for (int r = 0; r < 4; ++r) {
                int row = m0 + wm * 64 + mi * 16 + g * 4 + r;
                float val = acc[mi][ni][r] + bb;
                if (MODE == 0) {
                    int b = row >> 11, s = row & 2047;
                    if (col < 512) {
                        int h = col >> 6, d = col & 63;
                        Qws[(((size_t)(b * 8 + h) * NSEQ + s) << 6) + d] = f2bf(val * (SCALE * LOG2E));
                    } else if (col < 1024) {
                        int c2 = col - 512; int h = c2 >> 6, d = c2 & 63;
                        Kws[(((size_t)(b * 8 + h) * NSEQ + s) << 6) + d] = f2bf(val);
                    } else {
                        int c2 = col - 1024; int h = c2 >> 6, d = c2 & 63;
                        Vtws[((size_t)(b * 8 + h) * 64 + d) * NSEQ + s] = f2bf(val);
                    }
                } else {
                    Cout[(size_t)row * 512 + col] = val;
                }
            }
        }
    }
}

// ---------------- fused attention (R8 structure, K-swizzle conflict fix) -----
// Block = 512 thr = 8 waves, one (b,h); wave w owns 16 q-rows.
// K/V tiles dbuf in XOR-swizzled LDS (48KB). K-frag reads touch rows 4*fr+kf
// (stride-4 rows = 512B = bank-aliased), so K's swizzle is keyed on
// (row>>2)&7 -> 8 distinct bank-groups across the 16-lane group (2-way, free).
// R8's (row&7) gave only 2 groups -> 8-way conflict = 12.6M conflict cycles.
// V reads adjacent rows (nf*16+fr) -> keep (row&7). Fixed-max softmax.
__global__ __launch_bounds__(512, 3) void attn_kernel(
    const unsigned short* __restrict__ Qws,
    const unsigned short* __restrict__ Kws,
    const unsigned short* __restrict__ Vtws,
    const float* __restrict__ A_phi,
    const float* __restrict__ gamma_p,
    unsigned short* __restrict__ Oout)
{
    __shared__ __attribute__((aligned(16))) unsigned short Ks[2][64 * 64];
    __shared__ __attribute__((aligned(16))) unsigned short Vts[2][64 * 64];
    __shared__ __attribute__((aligned(16))) unsigned short Pl[8][16 * 64];

    int tid = threadIdx.x, lane = tid & 63, w = tid >> 6;
    int g = lane >> 4, fr = lane & 15;

    // swizzle: id%8 = XCD -> pin batch b to an XCD pair (A_phi L2 reuse)
    int id = blockIdx.x;                 // 0..511
    int b = (id & 7) >> 1, p = id & 1;
    int j = id >> 3;                     // 0..63
    int h = j & 7;
    int qt = ((j >> 3) << 1) | p;        // 0..15
    int bh = b * 8 + h;
    int q0 = qt * 128 + w * 16;          // wave's q base
    float g2 = gamma_p[0] * LOG2E;

    const unsigned short* Kb = Kws + (size_t)bh * NSEQ * 64;
    const unsigned short* Vb = Vtws + (size_t)bh * 64 * NSEQ;
    const float* Ap = A_phi + (size_t)b * NSEQ * NSEQ;

    // Q fragments
    short8v qf[2];
#pragma unroll
    for (int dc = 0; dc < 2; ++dc)
        qf[dc] = *(const short8v*)(Qws + ((size_t)bh * NSEQ + q0 + fr) * 64 + dc * 32 + g * 8);

    // staging: thread -> one 16B K chunk + one 16B V chunk
    int c = tid;
    int krow = c >> 3;                            // K: key 0..63 ; V: d 0..63
    int kchunk = c & 7;
    int swK = (kchunk ^ ((krow >> 2) & 7)) * 8;   // K: bank-group = f(row>>2)
    int swV = (kchunk ^ (krow & 7)) * 8;          // V: adjacent-row pattern
    int kcol = kchunk * 8;

    float l_lane[4] = {};
    f32x4 o_acc[4] = {};

    // prologue: stage tile 0
    {
        short8v k0v = *(const short8v*)(Kb + c * 8);
        short8v v0v = *(const short8v*)(Vb + (size_t)krow * NSEQ + kcol);
        *(short8v*)(&Ks[0][krow * 64 + swK]) = k0v;
        *(short8v*)(&Vts[0][krow * 64 + swV]) = v0v;
    }
    __syncthreads();

    for (int kt = 0; kt < NSEQ / 64; ++kt) {
        int cur = kt & 1;

        // T14: issue next-tile global loads early
        short8v kreg, vreg;
        if (kt < NSEQ / 64 - 1) {
            kreg = *(const short8v*)(Kb + (kt + 1) * 4096 + c * 8);
            vreg = *(const short8v*)(Vb + (size_t)krow * NSEQ + (kt + 1) * 64 + kcol);
        }

        // A_phi tile (coalesced float4; lane's 4 consecutive keys 4*fr..4*fr+3)
        float4 av[4];
#pragma unroll
        for (int r = 0; r < 4; ++r)
            av[r] = *(const float4*)(Ap + (size_t)(q0 + g * 4 + r) * NSEQ + kt * 64 + 4 * fr);

        // S = QK^T, permuted key order: chunk kf col fr = key 4*fr+kf
        f32x4 sa[4] = {};
        __builtin_amdgcn_s_setprio(1);
#pragma unroll
        for (int kf = 0; kf < 4; ++kf) {
            int row = 4 * fr + kf;
#pragma unroll
            for (int dc = 0; dc < 2; ++dc) {
                short8v kfrag = *(const short8v*)(
                    &Ks[cur][row * 64 + (((dc * 4 + g) ^ ((row >> 2) & 7)) * 8)]);
                sa[kf] = __builtin_amdgcn_mfma_f32_16x16x32_bf16(qf[dc], kfrag, sa[kf], 0, 0, 0);
            }
        }
        __builtin_amdgcn_s_setprio(0);

        // P = exp2(S + g2*A); per-lane l; relay to per-wave LDS (swizzled)
#pragma unroll
        for (int r = 0; r < 4; ++r) {
            float e0 = exp2_fast(fmaf(g2, av[r].x, sa[0][r]));
            float e1 = exp2_fast(fmaf(g2, av[r].y, sa[1][r]));
            float e2 = exp2_fast(fmaf(g2, av[r].z, sa[2][r]));
            float e3 = exp2_fast(fmaf(g2, av[r].w, sa[3][r]));
            l_lane[r] += (e0 + e1) + (e2 + e3);
            int rp = g * 4 + r;
            uint2 pp;
            pp.x = pack_bf16_rh(e0, e1);
            pp.y = pack_bf16_rh(e2, e3);
            *(uint2*)(&Pl[w][rp * 64 + (((fr >> 1) ^ (rp & 7)) * 8) + (fr & 1) * 4]) = pp;
        }
        asm volatile("s_waitcnt lgkmcnt(0)" ::: "memory");

        // O += P * V
#pragma unroll
        for (int kc = 0; kc < 2; ++kc) {
            short8v pf = *(const short8v*)(
                &Pl[w][fr * 64 + (((kc * 4 + g) ^ (fr & 7)) * 8)]);
            __builtin_amdgcn_s_setprio(1);
#pragma unroll
            for (int nf = 0; nf < 4; ++nf) {
                int vrow = nf * 16 + fr;
                short8v vf = *(const short8v*)(
                    &Vts[cur][vrow * 64 + (((kc * 4 + g) ^ (vrow & 7)) * 8)]);
                o_acc[nf] = __builtin_amdgcn_mfma_f32_16x16x32_bf16(pf, vf, o_acc[nf], 0, 0, 0);
            }
            __builtin_amdgcn_s_setprio(0);
        }

        // write staged regs into the other buffer, then block-wide barrier
        if (kt < NSEQ / 64 - 1) {
            *(short8v*)(&Ks[cur ^ 1][krow * 64 + swK]) = kreg;
            *(short8v*)(&Vts[cur ^ 1][krow * 64 + swV]) = vreg;
        }
        __syncthreads();
    }

    // epilogue: reduce l across 16-lane group, normalize, store bf16
#pragma unroll
    for (int r = 0; r < 4; ++r) {
        float l = l_lane[r];
        l += __shfl_xor(l, 1);
        l += __shfl_xor(l, 2);
        l += __shfl_xor(l, 4);
        l += __shfl_xor(l, 8);
        float inv = 1.0f / l;
        int qg = q0 + g * 4 + r;
#pragma unroll
        for (int nf = 0; nf < 4; ++nf)
            Oout[((size_t)b * NSEQ + qg) * 512 + h * 64 + nf * 16 + fr] =
                f2bf(o_acc[nf][r] * inv);
    }
}

extern "C" void kernel_launch(void* const* d_in, const int* in_sizes, int n_in,
                              void* d_out, int out_size, void* d_ws, size_t ws_size,
                              hipStream_t stream) {
    const float* x      = (const float*)d_in[0];
    const float* A_phi  = (const float*)d_in[1];
    const float* w_qkv  = (const float*)d_in[2];
    const float* b_qkv  = (const float*)d_in[3];
    const float* w_out  = (const float*)d_in[4];
    const float* b_out  = (const float*)d_in[5];
    const float* gamma  = (const float*)d_in[6];
    float* out = (float*)d_out;

    unsigned short* xb   = (unsigned short*)d_ws;
    unsigned short* wqb  = xb  + (size_t)8192 * 512;
    unsigned short* wob  = wqb + (size_t)1536 * 512;
    unsigned short* Qws  = wob + (size_t)512 * 512;
    unsigned short* Kws  = Qws + (size_t)4 * 8 * NSEQ * 64;
    unsigned short* Vtws = Kws + (size_t)4 * 8 * NSEQ * 64;
    unsigned short* Oat  = Vtws + (size_t)4 * 8 * NSEQ * 64;

    cvt_bf16<<<dim3(4096), dim3(256), 0, stream>>>(x, xb, 8192 * 512 / 4);
    cvt_bf16<<<dim3(768),  dim3(256), 0, stream>>>(w_qkv, wqb, 1536 * 512 / 4);
    cvt_bf16<<<dim3(256),  dim3(256), 0, stream>>>(w_out, wob, 512 * 512 / 4);

    gemm_bf16<0><<<dim3(12, 64), dim3(256), 0, stream>>>(
        xb, wqb, b_qkv, Qws, Kws, Vtws, nullptr);

    attn_kernel<<<dim3(512), dim3(512), 0, stream>>>(
        Qws, Kws, Vtws, A_phi, gamma, Oat);

    gemm_bf16<1><<<dim3(4, 64), dim3(256), 0, stream>>>(
        Oat, wob, b_out, nullptr, nullptr, nullptr, out);
}